// Round 4
// baseline (182.341 us; speedup 1.0000x reference)
//
#include <hip/hip_runtime.h>
#include <stdint.h>

#define B_  2
#define S_  2048
#define D_  1024
#define H_  16
#define HD_ 64
#define M_  (B_*S_)   // 4096 rows

typedef __bf16 bf16x8 __attribute__((ext_vector_type(8)));
typedef float  f32x4  __attribute__((ext_vector_type(4)));
typedef unsigned short u16x8 __attribute__((ext_vector_type(8)));

typedef const __attribute__((address_space(1))) void* gas_ptr;
typedef __attribute__((address_space(3))) void* las_ptr;

__device__ __forceinline__ uint16_t f32_to_bf16(float f) {
  uint32_t u = __float_as_uint(f);
  u += 0x7FFFu + ((u >> 16) & 1u);   // RNE; inputs are finite
  return (uint16_t)(u >> 16);
}

// RTZ: 1 VALU op; used only for P (positive, bias cancels in num/den)
__device__ __forceinline__ uint16_t f32_to_bf16_rtz(float f) {
  return (uint16_t)(__float_as_uint(f) >> 16);
}

__device__ __forceinline__ void g2l16(const uint16_t* g, uint16_t* l) {
  // async global->LDS: per-lane global addr; LDS dest = wave-uniform base + lane*16
  __builtin_amdgcn_global_load_lds((gas_ptr)g, (las_ptr)l, 16, 0, 0);
}

// ---------------- packed tile layout ----------------
// Matrix [R][1024] bf16 -> tiles: rtile (128 rows) x ktile (64 cols) x half
// (32 cols). Half-panel = 512 slots x 8 elems = 8KB, stored IN LDS IMAGE
// ORDER: slot(r, c4) = 4r + (c4 ^ ((r>>1)&3))  (the proven swizzle; read
// side unchanged). Staging a half-panel = identity copy of 8KB contiguous:
// every global_load_lds reads 1KB FULLY CONTIGUOUS (1 segment vs 16 before).
// POFF(rt,kt,h) = (((rt*16)+kt)*2+h)*4096 elements.
#define POFF(rt, kt, h) ((size_t)((((rt) * 16 + (kt)) * 2 + (h)) * 4096))

// cast+pack: fp32 row-major -> bf16 packed-tiled, for x + 4 weights.
// 1M chunks of 8 elems; thread i handles chunk i (32B read, 16B write).
__global__ void cast_pack(const float* __restrict__ x,
                          const float* __restrict__ wq, const float* __restrict__ wk,
                          const float* __restrict__ wv, const float* __restrict__ wf,
                          uint16_t* __restrict__ xb,
                          uint16_t* __restrict__ wqb, uint16_t* __restrict__ wkb,
                          uint16_t* __restrict__ wvb, uint16_t* __restrict__ wfb) {
  const int XC = M_ * D_ / 8;        // 512K chunks in x
  const int WC = D_ * D_ / 8;        // 128K chunks per weight
  int i = blockIdx.x * 256 + threadIdx.x;
  const float* src; uint16_t* dst; int off;
  if (i < XC) { src = x; dst = xb; off = i; }
  else {
    int j = i - XC;
    int w = j >> 17;                 // / WC
    off = j & (WC - 1);
    src = (w == 0) ? wq : (w == 1) ? wk : (w == 2) ? wv : wf;
    dst = (w == 0) ? wqb : (w == 1) ? wkb : (w == 2) ? wvb : wfb;
  }
  const int row = off >> 7;          // 128 chunks per row
  const int c   = off & 127;
  const float4 v0 = ((const float4*)src)[row * 256 + c * 2];
  const float4 v1 = ((const float4*)src)[row * 256 + c * 2 + 1];
  u16x8 o;
  o[0] = f32_to_bf16(v0.x); o[1] = f32_to_bf16(v0.y);
  o[2] = f32_to_bf16(v0.z); o[3] = f32_to_bf16(v0.w);
  o[4] = f32_to_bf16(v1.x); o[5] = f32_to_bf16(v1.y);
  o[6] = f32_to_bf16(v1.z); o[7] = f32_to_bf16(v1.w);
  const int kt = c >> 3, c8 = c & 7, h = c8 >> 2, c4 = c8 & 3;
  const int rt = row >> 7, r = row & 127;
  const int s = 4 * r + (c4 ^ ((r >> 1) & 3));
  *(u16x8*)(dst + POFF(rt, kt, h) + s * 8) = o;
}

// qkv_gemm v5: 128x128 tile, BK=64, 4 waves 2x2 (64x64/wave), grid 768
// (3 outputs x 8 ntiles x 32 mtiles), 64KB dbuf LDS -> 2 blocks/CU (block-
// level TLP covers prologue/epilogue/stalls -- the knob no prior variant
// moved). Staging from PACKED buffers: 8 g2l16/thread/K-tile, each 1KB
// contiguous (1 memory segment vs 16 in v2-v4). Prefetch next tile BEFORE
// compute, one __syncthreads per tile (flash-v6 pattern that worked).
// Q,K -> [B,H,S,HD]; V -> transposed [B,H,HD,S]. Q pre-scaled 0.125*log2(e).
__global__ __launch_bounds__(256, 2)
void qkv_gemm(const uint16_t* __restrict__ xb,
              const uint16_t* __restrict__ wqb, const uint16_t* __restrict__ wkb,
              const uint16_t* __restrict__ wvb,
              const float* __restrict__ bqv, const float* __restrict__ bkv,
              const float* __restrict__ bvv,
              uint16_t* __restrict__ qout, uint16_t* __restrict__ kout,
              uint16_t* __restrict__ vtout)
{
  __shared__ __align__(16) uint16_t As[2][2][4096];   // [buf][khalf][512 slots*8]
  __shared__ __align__(16) uint16_t Bs[2][2][4096];

  const int wsel = blockIdx.x >> 3;          // 0=Q 1=K 2=V
  const int nsel = blockIdx.x & 7;
  const int mtile = blockIdx.y;
  const int tid  = threadIdx.x;
  const int lane = tid & 63, wave = tid >> 6;
  const int quad = lane >> 4, l16 = lane & 15;
  const int wm = (wave >> 1) * 64, wn = (wave & 1) * 64;
  const int sw = quad ^ ((l16 >> 1) & 3);

  const uint16_t *Ap, *Bp;
  int art, brt, m0e, n0e;
  if (wsel < 2) {
    Ap = xb; art = mtile; Bp = (wsel == 0) ? wqb : wkb; brt = nsel;
    m0e = mtile * 128; n0e = nsel * 128;
  } else {
    Ap = wvb; art = nsel; Bp = xb; brt = mtile;
    m0e = nsel * 128; n0e = mtile * 128;
  }

  // staging addressing: issue i covers slots i*256+tid (contiguous copy)
  const int se0 = tid * 8;                    // elem offset, issue 0
  const int se1 = (256 + tid) * 8;            // issue 1
  const int ld0 = (wave * 64) * 8;            // wave-uniform LDS bases
  const int ld1 = (256 + wave * 64) * 8;

  f32x4 acc[4][4];
  #pragma unroll
  for (int i = 0; i < 4; ++i)
    #pragma unroll
    for (int j = 0; j < 4; ++j)
      #pragma unroll
      for (int e = 0; e < 4; ++e)
        acc[i][j][e] = 0.f;

  // prologue: stage tile 0 -> buf 0
  #pragma unroll
  for (int h = 0; h < 2; ++h) {
    g2l16(Ap + POFF(art, 0, h) + se0, &As[0][h][ld0]);
    g2l16(Ap + POFF(art, 0, h) + se1, &As[0][h][ld1]);
    g2l16(Bp + POFF(brt, 0, h) + se0, &Bs[0][h][ld0]);
    g2l16(Bp + POFF(brt, 0, h) + se1, &Bs[0][h][ld1]);
  }
  __syncthreads();

  for (int t = 0; t < 16; ++t) {
    const int cb = t & 1, cn = cb ^ 1;
    if (t < 15) {        // prefetch next K-tile; latency hides under compute
      #pragma unroll
      for (int h = 0; h < 2; ++h) {
        g2l16(Ap + POFF(art, t + 1, h) + se0, &As[cn][h][ld0]);
        g2l16(Ap + POFF(art, t + 1, h) + se1, &As[cn][h][ld1]);
        g2l16(Bp + POFF(brt, t + 1, h) + se0, &Bs[cn][h][ld0]);
        g2l16(Bp + POFF(brt, t + 1, h) + se1, &Bs[cn][h][ld1]);
      }
    }
    bf16x8 af[4][2], bf[4][2];
    #pragma unroll
    for (int mt = 0; mt < 4; ++mt) {
      const int ro = ((wm + mt * 16 + l16) * 4 + sw) * 8;
      af[mt][0] = *(const bf16x8*)(&As[cb][0][ro]);
      af[mt][1] = *(const bf16x8*)(&As[cb][1][ro]);
    }
    #pragma unroll
    for (int nt = 0; nt < 4; ++nt) {
      const int ro = ((wn + nt * 16 + l16) * 4 + sw) * 8;
      bf[nt][0] = *(const bf16x8*)(&Bs[cb][0][ro]);
      bf[nt][1] = *(const bf16x8*)(&Bs[cb][1][ro]);
    }
    __builtin_amdgcn_s_setprio(1);
    #pragma unroll
    for (int mt = 0; mt < 4; ++mt)
      #pragma unroll
      for (int nt = 0; nt < 4; ++nt) {
        acc[mt][nt] = __builtin_amdgcn_mfma_f32_16x16x32_bf16(
            af[mt][0], bf[nt][0], acc[mt][nt], 0, 0, 0);
        acc[mt][nt] = __builtin_amdgcn_mfma_f32_16x16x32_bf16(
            af[mt][1], bf[nt][1], acc[mt][nt], 0, 0, 0);
      }
    __builtin_amdgcn_s_setprio(0);
    __syncthreads();   // drains prefetch (covered by compute) + read-done
  }

  if (wsel < 2) {
    const float* bias = (wsel == 0) ? bqv : bkv;
    uint16_t* outp = (wsel == 0) ? qout : kout;
    const float scl = (wsel == 0) ? 0.18033688f : 1.0f;
    #pragma unroll
    for (int nt = 0; nt < 4; ++nt) {
      const int n = n0e + wn + nt * 16 + l16;
      const int h = n >> 6, hd = n & 63;
      const float bia = bias[n];
      #pragma unroll
      for (int mt = 0; mt < 4; ++mt) {
        #pragma unroll
        for (int r = 0; r < 4; ++r) {
          const int m = m0e + wm + mt * 16 + quad * 4 + r;
          const int bb = m >> 11, s = m & (S_ - 1);
          outp[(((size_t)(bb * H_ + h)) * S_ + s) * HD_ + hd] =
              f32_to_bf16((acc[mt][nt][r] + bia) * scl);
        }
      }
    }
  } else {
    #pragma unroll
    for (int mt = 0; mt < 4; ++mt) {
      #pragma unroll
      for (int r = 0; r < 4; ++r) {
        const int m = m0e + wm + mt * 16 + quad * 4 + r;
        const int h = m >> 6, hd = m & 63;
        const float bia = bvv[m];
        #pragma unroll
        for (int nt = 0; nt < 4; ++nt) {
          const int n = n0e + wn + nt * 16 + l16;
          const int bb = n >> 11, s = n & (S_ - 1);
          vtout[(((size_t)(bb * H_ + h)) * HD_ + hd) * S_ + s] =
              f32_to_bf16(acc[mt][nt][r] + bia);
        }
      }
    }
  }
}

// flash v6: double-buffered K/V across key-tiles; prefetch before compute;
// setprio around MFMA clusters. Output now written in PACKED layout so
// out_gemm gets contiguous staging. LDS 41.2KB -> 3 blocks/CU.
__global__ __launch_bounds__(256)
void flash_attn(const uint16_t* __restrict__ qb, const uint16_t* __restrict__ kb,
                const uint16_t* __restrict__ vtb, uint16_t* __restrict__ ao)
{
  __shared__ __align__(16) uint16_t ks[2][2][2048];   // [buf][chunk c][64r x 32c]
  __shared__ __align__(16) uint16_t vs[2][2][2048];   // [buf][chunk c][64hd x 32k]
  __shared__ __align__(16) uint16_t p_lds[4][16][72]; // P transpose, wave-private

  const int bh = blockIdx.x;
  const int qt = (int)(gridDim.y - 1u - blockIdx.y);  // heavy blocks first
  const int wave = threadIdx.x >> 6, lane = threadIdx.x & 63;
  const int quad = lane >> 4, l16 = lane & 15;
  const int sw = quad ^ ((l16 >> 1) & 3);
  const int q0 = qt * 64;

  const uint16_t* Q  = qb  + (size_t)bh * S_ * HD_;
  const uint16_t* Kp = kb  + (size_t)bh * S_ * HD_;
  const uint16_t* Vt = vtb + (size_t)bh * HD_ * S_;

  // Q fragments for this wave's 16 rows: A[m=l16][k=quad*8+j]
  const int qrow = q0 + wave * 16;
  bf16x8 aq0 = *(const bf16x8*)(Q + (size_t)(qrow + l16) * HD_ + quad * 8);
  bf16x8 aq1 = *(const bf16x8*)(Q + (size_t)(qrow + l16) * HD_ + 32 + quad * 8);

  // staging: 16 x 1KB groups per tile; wave w handles groups 4w..4w+3.
  // groups 0-7: K (chunk g>>2, rowblk g&3); 8-15: V^T likewise. Swizzled fill.
  const int srow = lane >> 2;                       // local row 0..15
  const int schk = (lane & 3) ^ ((lane >> 3) & 3);  // swizzled source chunk
  const uint16_t* sb[4]; uint16_t* sd0[4]; uint16_t* sd1[4]; int sstep[4];
  #pragma unroll
  for (int j = 0; j < 4; ++j) {
    const int g = wave * 4 + j;
    if (g < 8) {
      const int c = (g >> 2) & 1, rb = g & 3;
      sd0[j] = &ks[0][c][rb * 512];
      sd1[j] = &ks[1][c][rb * 512];
      sb[j] = Kp + (size_t)(rb * 16 + srow) * HD_ + c * 32 + schk * 8;
      sstep[j] = 64 * HD_;          // advance 64 key-rows per tile
    } else {
      const int gg = g - 8, c = (gg >> 2) & 1, rb = gg & 3;
      sd0[j] = &vs[0][c][rb * 512];
      sd1[j] = &vs[1][c][rb * 512];
      sb[j] = Vt + (size_t)(rb * 16 + srow) * S_ + c * 32 + schk * 8;
      sstep[j] = 64;                // advance 64 key-cols per tile
    }
  }

  float lpart[4];
  f32x4 o[4];
  #pragma unroll
  for (int r = 0; r < 4; ++r) lpart[r] = 0.f;
  #pragma unroll
  for (int t = 0; t < 4; ++t)
    #pragma unroll
    for (int e = 0; e < 4; ++e) o[t][e] = 0.f;

  const int rowid = qrow + quad * 4;    // +r = this lane's score rows

  // prologue: stage tile 0 into buf 0
  #pragma unroll
  for (int j = 0; j < 4; ++j) {
    g2l16(sb[j], sd0[j]);
    sb[j] += sstep[j];
  }
  __syncthreads();

  for (int kt = 0; kt <= qt; ++kt) {
    const int kbase = kt * 64;
    const bool diag = (kt == qt);
    const int cb = kt & 1;

    // prefetch tile kt+1 into the other buffer; latency hides under compute
    if (kt < qt) {
      #pragma unroll
      for (int j = 0; j < 4; ++j) {
        g2l16(sb[j], cb ? sd0[j] : sd1[j]);
        sb[j] += sstep[j];
      }
    }

    bf16x8 kf0[4], kf1[4];
    #pragma unroll
    for (int nt = 0; nt < 4; ++nt) {
      kf0[nt] = *(const bf16x8*)(&ks[cb][0][((nt * 16 + l16) * 4 + sw) * 8]);
      kf1[nt] = *(const bf16x8*)(&ks[cb][1][((nt * 16 + l16) * 4 + sw) * 8]);
    }
    f32x4 sacc[4];
    __builtin_amdgcn_s_setprio(1);
    #pragma unroll
    for (int nt = 0; nt < 4; ++nt) {
      #pragma unroll
      for (int e = 0; e < 4; ++e) sacc[nt][e] = 0.f;
      sacc[nt] = __builtin_amdgcn_mfma_f32_16x16x32_bf16(aq0, kf0[nt], sacc[nt], 0, 0, 0);
      sacc[nt] = __builtin_amdgcn_mfma_f32_16x16x32_bf16(aq1, kf1[nt], sacc[nt], 0, 0, 0);
    }
    __builtin_amdgcn_s_setprio(0);

    bf16x8 vf0[4], vf1[4];
    #pragma unroll
    for (int t = 0; t < 4; ++t) {
      vf0[t] = *(const bf16x8*)(&vs[cb][0][((t * 16 + l16) * 4 + sw) * 8]);
      vf1[t] = *(const bf16x8*)(&vs[cb][1][((t * 16 + l16) * 4 + sw) * 8]);
    }

    // max-free softmax: p = exp2(s) (log2e folded into Q); masked -> 0; RTZ
    #pragma unroll
    for (int nt = 0; nt < 4; ++nt) {
      const int kkc = kbase + nt * 16 + l16;
      #pragma unroll
      for (int r = 0; r < 4; ++r) {
        float p = __builtin_amdgcn_exp2f(sacc[nt][r]);
        if (diag && (kkc > rowid + r)) p = 0.f;
        lpart[r] += p;
        p_lds[wave][quad * 4 + r][nt * 16 + l16] = f32_to_bf16_rtz(p);
      }
    }

    // P: C-layout -> A-layout via wave-private LDS (DS ops in-order per wave)
    bf16x8 ap0 = *(const bf16x8*)(&p_lds[wave][l16][quad * 8]);
    bf16x8 ap1 = *(const bf16x8*)(&p_lds[wave][l16][32 + quad * 8]);
    __builtin_amdgcn_s_setprio(1);
    #pragma unroll
    for (int t = 0; t < 4; ++t) {      // O += P V
      o[t] = __builtin_amdgcn_mfma_f32_16x16x32_bf16(ap0, vf0[t], o[t], 0, 0, 0);
      o[t] = __builtin_amdgcn_mfma_f32_16x16x32_bf16(ap1, vf1[t], o[t], 0, 0, 0);
    }
    __builtin_amdgcn_s_setprio(0);
    __syncthreads();    // prefetch landed + all waves done reading buf cb
  }

  // wave-complete rows: butterfly row-sum, then store (PACKED layout)
  #pragma unroll
  for (int r = 0; r < 4; ++r) {
    lpart[r] += __shfl_xor(lpart[r], 1, 64);
    lpart[r] += __shfl_xor(lpart[r], 2, 64);
    lpart[r] += __shfl_xor(lpart[r], 4, 64);
    lpart[r] += __shfl_xor(lpart[r], 8, 64);
  }
  const int bb = bh >> 4, h = bh & 15;    // kt index for packed out = h
  #pragma unroll
  for (int t = 0; t < 4; ++t) {
    const int c8 = t * 2 + (l16 >> 3);    // col-in-ktile / 8
    const int hh = c8 >> 2, c4 = c8 & 3, e = l16 & 7;
    #pragma unroll
    for (int r = 0; r < 4; ++r) {
      const float ov = o[t][r] / lpart[r];
      const int grow = bb * S_ + rowid + r;
      const int rt = grow >> 7, rr = grow & 127;
      const int s = 4 * rr + (c4 ^ ((rr >> 1) & 3));
      ao[POFF(rt, h, hh) + s * 8 + e] = f32_to_bf16(ov);
    }
  }
}

// out_gemm v4: 128x128 tile from PACKED aob/wfb, same dbuf prefetch loop as
// qkv v5. grid (8, 32) = 256 blocks. fp32 output row-major + bias.
__global__ __launch_bounds__(256, 2)
void out_gemm(const uint16_t* __restrict__ ab, const uint16_t* __restrict__ wfb,
              const float* __restrict__ bfv, float* __restrict__ out)
{
  __shared__ __align__(16) uint16_t As[2][2][4096];
  __shared__ __align__(16) uint16_t Bs[2][2][4096];
  const int nsel = blockIdx.x;               // 8 weight N-tiles
  const int mtile = blockIdx.y;              // 32 m-tiles
  const int tid  = threadIdx.x;
  const int lane = tid & 63, wave = tid >> 6;
  const int quad = lane >> 4, l16 = lane & 15;
  const int wm = (wave >> 1) * 64, wn = (wave & 1) * 64;
  const int sw = quad ^ ((l16 >> 1) & 3);

  const int se0 = tid * 8, se1 = (256 + tid) * 8;
  const int ld0 = (wave * 64) * 8, ld1 = (256 + wave * 64) * 8;

  f32x4 acc[4][4];
  #pragma unroll
  for (int i = 0; i < 4; ++i)
    #pragma unroll
    for (int j = 0; j < 4; ++j)
      #pragma unroll
      for (int e = 0; e < 4; ++e)
        acc[i][j][e] = 0.f;

  #pragma unroll
  for (int h = 0; h < 2; ++h) {
    g2l16(ab  + POFF(mtile, 0, h) + se0, &As[0][h][ld0]);
    g2l16(ab  + POFF(mtile, 0, h) + se1, &As[0][h][ld1]);
    g2l16(wfb + POFF(nsel, 0, h) + se0, &Bs[0][h][ld0]);
    g2l16(wfb + POFF(nsel, 0, h) + se1, &Bs[0][h][ld1]);
  }
  __syncthreads();

  for (int t = 0; t < 16; ++t) {
    const int cb = t & 1, cn = cb ^ 1;
    if (t < 15) {
      #pragma unroll
      for (int h = 0; h < 2; ++h) {
        g2l16(ab  + POFF(mtile, t + 1, h) + se0, &As[cn][h][ld0]);
        g2l16(ab  + POFF(mtile, t + 1, h) + se1, &As[cn][h][ld1]);
        g2l16(wfb + POFF(nsel, t + 1, h) + se0, &Bs[cn][h][ld0]);
        g2l16(wfb + POFF(nsel, t + 1, h) + se1, &Bs[cn][h][ld1]);
      }
    }
    bf16x8 af[4][2], bf[4][2];
    #pragma unroll
    for (int mt = 0; mt < 4; ++mt) {
      const int ro = ((wm + mt * 16 + l16) * 4 + sw) * 8;
      af[mt][0] = *(const bf16x8*)(&As[cb][0][ro]);
      af[mt][1] = *(const bf16x8*)(&As[cb][1][ro]);
    }
    #pragma unroll
    for (int nt = 0; nt < 4; ++nt) {
      const int ro = ((wn + nt * 16 + l16) * 4 + sw) * 8;
      bf[nt][0] = *(const bf16x8*)(&Bs[cb][0][ro]);
      bf[nt][1] = *(const bf16x8*)(&Bs[cb][1][ro]);
    }
    __builtin_amdgcn_s_setprio(1);
    #pragma unroll
    for (int mt = 0; mt < 4; ++mt)
      #pragma unroll
      for (int nt = 0; nt < 4; ++nt) {
        acc[mt][nt] = __builtin_amdgcn_mfma_f32_16x16x32_bf16(
            af[mt][0], bf[nt][0], acc[mt][nt], 0, 0, 0);
        acc[mt][nt] = __builtin_amdgcn_mfma_f32_16x16x32_bf16(
            af[mt][1], bf[nt][1], acc[mt][nt], 0, 0, 0);
      }
    __builtin_amdgcn_s_setprio(0);
    __syncthreads();
  }

  const int m0 = mtile * 128, n0 = nsel * 128;
  #pragma unroll
  for (int nt = 0; nt < 4; ++nt) {
    const int n = n0 + wn + nt * 16 + l16;
    const float bia = bfv[n];
    #pragma unroll
    for (int mt = 0; mt < 4; ++mt) {
      #pragma unroll
      for (int r = 0; r < 4; ++r) {
        const int m = m0 + wm + mt * 16 + quad * 4 + r;
        out[(size_t)m * D_ + n] = acc[mt][nt][r] + bia;
      }
    }
  }
}

extern "C" void kernel_launch(void* const* d_in, const int* in_sizes, int n_in,
                              void* d_out, int out_size, void* d_ws, size_t ws_size,
                              hipStream_t stream) {
  (void)in_sizes; (void)n_in; (void)out_size; (void)ws_size;
  const float* x  = (const float*)d_in[0];
  const float* Wq = (const float*)d_in[1];
  const float* bq = (const float*)d_in[2];
  const float* Wk = (const float*)d_in[3];
  const float* bk = (const float*)d_in[4];
  const float* Wv = (const float*)d_in[5];
  const float* bv = (const float*)d_in[6];
  const float* Wf = (const float*)d_in[7];
  const float* bf = (const float*)d_in[8];
  float* out = (float*)d_out;

  uint16_t* ws = (uint16_t*)d_ws;
  uint16_t* xb   = ws;
  uint16_t* wqb  = xb  + (size_t)M_ * D_;
  uint16_t* wkb  = wqb + (size_t)D_ * D_;
  uint16_t* wvb  = wkb + (size_t)D_ * D_;
  uint16_t* wfb  = wvb + (size_t)D_ * D_;
  uint16_t* qbuf = wfb + (size_t)D_ * D_;
  uint16_t* kbuf = qbuf + (size_t)M_ * D_;
  uint16_t* vtb  = kbuf + (size_t)M_ * D_;
  uint16_t* aob  = vtb  + (size_t)M_ * D_;

  const int CAST_BLOCKS = (M_ * D_ / 8 + 4 * (D_ * D_ / 8)) / 256;   // 4096
  cast_pack<<<CAST_BLOCKS, 256, 0, stream>>>(x, Wq, Wk, Wv, Wf,
                                             xb, wqb, wkb, wvb, wfb);

  qkv_gemm<<<dim3(24, 32), 256, 0, stream>>>(xb, wqb, wkb, wvb, bq, bk, bv,
                                             qbuf, kbuf, vtb);
  flash_attn<<<dim3(32, 32), 256, 0, stream>>>(qbuf, kbuf, vtb, aob);
  out_gemm<<<dim3(8, 32), 256, 0, stream>>>(aob, wfb, bf, out);
}

// Round 5
// 180.483 us; speedup vs baseline: 1.0103x; 1.0103x over previous
//
#include <hip/hip_runtime.h>
#include <stdint.h>

#define B_  2
#define S_  2048
#define D_  1024
#define H_  16
#define HD_ 64
#define M_  (B_*S_)   // 4096 rows

typedef __bf16 bf16x8 __attribute__((ext_vector_type(8)));
typedef float  f32x4  __attribute__((ext_vector_type(4)));
typedef unsigned short u16x8 __attribute__((ext_vector_type(8)));

typedef const __attribute__((address_space(1))) void* gas_ptr;
typedef __attribute__((address_space(3))) void* las_ptr;

__device__ __forceinline__ uint16_t f32_to_bf16(float f) {
  uint32_t u = __float_as_uint(f);
  u += 0x7FFFu + ((u >> 16) & 1u);   // RNE; inputs are finite
  return (uint16_t)(u >> 16);
}

// RTZ: 1 VALU op; used only for P (positive, bias cancels in num/den)
__device__ __forceinline__ uint16_t f32_to_bf16_rtz(float f) {
  return (uint16_t)(__float_as_uint(f) >> 16);
}

__device__ __forceinline__ void g2l16(const uint16_t* g, uint16_t* l) {
  // async global->LDS: per-lane global addr; LDS dest = wave-uniform base + lane*16
  __builtin_amdgcn_global_load_lds((gas_ptr)g, (las_ptr)l, 16, 0, 0);
}

// ---------------- packed tile layout ----------------
// Matrix [R][1024] bf16 -> tiles: rtile (128 rows) x ktile (64 cols) x half
// (32 cols). Half-panel = 512 slots x 8 elems = 8KB, stored IN LDS IMAGE
// ORDER: slot(r, c4) = 4r + (c4 ^ ((r>>1)&3)). Staging a half-panel =
// identity copy of 8KB contiguous global memory.
// POFF(rt,kt,h) = (((rt*16)+kt)*2+h)*4096 elements.
#define POFF(rt, kt, h) ((size_t)((((rt) * 16 + (kt)) * 2 + (h)) * 4096))

// cast+pack: fp32 row-major -> bf16 packed-tiled, for x + 4 weights.
__global__ void cast_pack(const float* __restrict__ x,
                          const float* __restrict__ wq, const float* __restrict__ wk,
                          const float* __restrict__ wv, const float* __restrict__ wf,
                          uint16_t* __restrict__ xb,
                          uint16_t* __restrict__ wqb, uint16_t* __restrict__ wkb,
                          uint16_t* __restrict__ wvb, uint16_t* __restrict__ wfb) {
  const int XC = M_ * D_ / 8;        // 512K chunks in x
  const int WC = D_ * D_ / 8;        // 128K chunks per weight
  int i = blockIdx.x * 256 + threadIdx.x;
  const float* src; uint16_t* dst; int off;
  if (i < XC) { src = x; dst = xb; off = i; }
  else {
    int j = i - XC;
    int w = j >> 17;                 // / WC
    off = j & (WC - 1);
    src = (w == 0) ? wq : (w == 1) ? wk : (w == 2) ? wv : wf;
    dst = (w == 0) ? wqb : (w == 1) ? wkb : (w == 2) ? wvb : wfb;
  }
  const int row = off >> 7;          // 128 chunks per row
  const int c   = off & 127;
  const float4 v0 = ((const float4*)src)[row * 256 + c * 2];
  const float4 v1 = ((const float4*)src)[row * 256 + c * 2 + 1];
  u16x8 o;
  o[0] = f32_to_bf16(v0.x); o[1] = f32_to_bf16(v0.y);
  o[2] = f32_to_bf16(v0.z); o[3] = f32_to_bf16(v0.w);
  o[4] = f32_to_bf16(v1.x); o[5] = f32_to_bf16(v1.y);
  o[6] = f32_to_bf16(v1.z); o[7] = f32_to_bf16(v1.w);
  const int kt = c >> 3, c8 = c & 7, h = c8 >> 2, c4 = c8 & 3;
  const int rt = row >> 7, r = row & 127;
  const int s = 4 * r + (c4 ^ ((r >> 1) & 3));
  *(u16x8*)(dst + POFF(rt, kt, h) + s * 8) = o;
}

// qkv_gemm v6: 256(M)x128(N) tile, BK=32, 4 waves (2Mx2N: 128x64/wave).
// Combines for the first time: (a) staging reuse 24B/output-elem (302MB
// total through L2, ~9us floor), (b) dbuf LDS only 48KB + ~90 arch-VGPR ->
// 2 RESIDENT BLOCKS/CU (inter-block overlap covers the per-tile sync), (c)
// full grid: 384 blocks on 256 CUs. Proven pieces kept: packed contiguous
// g2l staging, prefetch-next-tile-before-compute, one __syncthreads/tile,
// 16x16x32 MFMA + proven fragment/epilogue layouts, setprio around MFMA.
// grid (24, 16): x = wsel*8 + nsel, y = mtile.
__global__ __launch_bounds__(256, 2)
void qkv_gemm(const uint16_t* __restrict__ xb,
              const uint16_t* __restrict__ wqb, const uint16_t* __restrict__ wkb,
              const uint16_t* __restrict__ wvb,
              const float* __restrict__ bqv, const float* __restrict__ bkv,
              const float* __restrict__ bvv,
              uint16_t* __restrict__ qout, uint16_t* __restrict__ kout,
              uint16_t* __restrict__ vtout)
{
  // per buf: A = 2 half-panels (256 rows x 32 cols) 16KB, B = 1 (128x32) 8KB
  __shared__ __align__(16) uint16_t As[2][2][4096];   // [buf][rhalf][8KB panel]
  __shared__ __align__(16) uint16_t Bs[2][4096];      // [buf][8KB panel]

  const int wsel = blockIdx.x >> 3;          // 0=Q 1=K 2=V
  const int nsel = blockIdx.x & 7;
  const int mtile = blockIdx.y;
  const int tid  = threadIdx.x;
  const int lane = tid & 63, wave = tid >> 6;
  const int quad = lane >> 4, l16 = lane & 15;
  const int wm = (wave >> 1) * 128;          // wave row offset in 256
  const int wn = (wave & 1) * 64;            // wave col offset in 128
  const int rh = wave >> 1;                  // A panel this wave reads
  const int sw = quad ^ ((l16 >> 1) & 3);

  const uint16_t *Ap, *Bp;
  int art, brt, m0e, n0e;
  if (wsel < 2) {
    Ap = xb; art = mtile * 2;                // two stacked 128-row A tiles
    Bp = (wsel == 0) ? wqb : wkb; brt = nsel;
    m0e = mtile * 256; n0e = nsel * 128;
  } else {
    // V: A = Wv (1024 rows -> 4 tiles of 256), B = x (4096 rows -> 32 of 128)
    const int idv = nsel + 8 * mtile;        // 0..127
    const int artv = idv >> 5;               // 0..3
    const int brtv = idv & 31;               // 0..31
    Ap = wvb; art = artv * 2; Bp = xb; brt = brtv;
    m0e = artv * 256; n0e = brtv * 128;
  }

  // staging: each 8KB panel filled by 2 issues of 256 threads x 16B
  const int se0 = tid * 8;                    // elem offset, issue 0
  const int se1 = (256 + tid) * 8;            // issue 1
  const int ld0 = (wave * 64) * 8;            // wave-uniform LDS bases
  const int ld1 = (256 + wave * 64) * 8;

  f32x4 acc[8][4];
  #pragma unroll
  for (int i = 0; i < 8; ++i)
    #pragma unroll
    for (int j = 0; j < 4; ++j)
      #pragma unroll
      for (int e = 0; e < 4; ++e)
        acc[i][j][e] = 0.f;

  // prologue: stage K-tile 0 (kt=0, h=0) -> buf 0 (6 g2l16/thread)
  g2l16(Ap + POFF(art,     0, 0) + se0, &As[0][0][ld0]);
  g2l16(Ap + POFF(art,     0, 0) + se1, &As[0][0][ld1]);
  g2l16(Ap + POFF(art + 1, 0, 0) + se0, &As[0][1][ld0]);
  g2l16(Ap + POFF(art + 1, 0, 0) + se1, &As[0][1][ld1]);
  g2l16(Bp + POFF(brt,     0, 0) + se0, &Bs[0][ld0]);
  g2l16(Bp + POFF(brt,     0, 0) + se1, &Bs[0][ld1]);
  __syncthreads();

  for (int t = 0; t < 32; ++t) {             // 32 K-steps of 32
    const int cb = t & 1, cn = cb ^ 1;
    if (t < 31) {        // prefetch next K-step; latency hides under compute
      const int kt = (t + 1) >> 1, h = (t + 1) & 1;
      g2l16(Ap + POFF(art,     kt, h) + se0, &As[cn][0][ld0]);
      g2l16(Ap + POFF(art,     kt, h) + se1, &As[cn][0][ld1]);
      g2l16(Ap + POFF(art + 1, kt, h) + se0, &As[cn][1][ld0]);
      g2l16(Ap + POFF(art + 1, kt, h) + se1, &As[cn][1][ld1]);
      g2l16(Bp + POFF(brt,     kt, h) + se0, &Bs[cn][ld0]);
      g2l16(Bp + POFF(brt,     kt, h) + se1, &Bs[cn][ld1]);
    }
    bf16x8 af[8], bf[4];
    #pragma unroll
    for (int mt = 0; mt < 8; ++mt)
      af[mt] = *(const bf16x8*)(&As[cb][rh][((mt * 16 + l16) * 4 + sw) * 8]);
    #pragma unroll
    for (int nt = 0; nt < 4; ++nt)
      bf[nt] = *(const bf16x8*)(&Bs[cb][((wn + nt * 16 + l16) * 4 + sw) * 8]);
    __builtin_amdgcn_s_setprio(1);
    #pragma unroll
    for (int mt = 0; mt < 8; ++mt)
      #pragma unroll
      for (int nt = 0; nt < 4; ++nt)
        acc[mt][nt] = __builtin_amdgcn_mfma_f32_16x16x32_bf16(
            af[mt], bf[nt], acc[mt][nt], 0, 0, 0);
    __builtin_amdgcn_s_setprio(0);
    __syncthreads();   // drains prefetch (covered by compute) + read-done
  }

  if (wsel < 2) {
    const float* bias = (wsel == 0) ? bqv : bkv;
    uint16_t* outp = (wsel == 0) ? qout : kout;
    const float scl = (wsel == 0) ? 0.18033688f : 1.0f;
    #pragma unroll
    for (int nt = 0; nt < 4; ++nt) {
      const int n = n0e + wn + nt * 16 + l16;
      const int h = n >> 6, hd = n & 63;
      const float bia = bias[n];
      #pragma unroll
      for (int mt = 0; mt < 8; ++mt) {
        #pragma unroll
        for (int r = 0; r < 4; ++r) {
          const int m = m0e + wm + mt * 16 + quad * 4 + r;
          const int bb = m >> 11, s = m & (S_ - 1);
          outp[(((size_t)(bb * H_ + h)) * S_ + s) * HD_ + hd] =
              f32_to_bf16((acc[mt][nt][r] + bia) * scl);
        }
      }
    }
  } else {
    #pragma unroll
    for (int mt = 0; mt < 8; ++mt) {
      #pragma unroll
      for (int r = 0; r < 4; ++r) {
        const int m = m0e + wm + mt * 16 + quad * 4 + r;   // weight row
        const int h = m >> 6, hd = m & 63;
        const float bia = bvv[m];
        #pragma unroll
        for (int nt = 0; nt < 4; ++nt) {
          const int n = n0e + wn + nt * 16 + l16;          // sequence
          const int bb = n >> 11, s = n & (S_ - 1);
          vtout[(((size_t)(bb * H_ + h)) * HD_ + hd) * S_ + s] =
              f32_to_bf16(acc[mt][nt][r] + bia);
        }
      }
    }
  }
}

// flash v6: double-buffered K/V across key-tiles; prefetch before compute;
// setprio around MFMA clusters; PACKED-layout output for out_gemm staging.
__global__ __launch_bounds__(256)
void flash_attn(const uint16_t* __restrict__ qb, const uint16_t* __restrict__ kb,
                const uint16_t* __restrict__ vtb, uint16_t* __restrict__ ao)
{
  __shared__ __align__(16) uint16_t ks[2][2][2048];   // [buf][chunk c][64r x 32c]
  __shared__ __align__(16) uint16_t vs[2][2][2048];   // [buf][chunk c][64hd x 32k]
  __shared__ __align__(16) uint16_t p_lds[4][16][72]; // P transpose, wave-private

  const int bh = blockIdx.x;
  const int qt = (int)(gridDim.y - 1u - blockIdx.y);  // heavy blocks first
  const int wave = threadIdx.x >> 6, lane = threadIdx.x & 63;
  const int quad = lane >> 4, l16 = lane & 15;
  const int sw = quad ^ ((l16 >> 1) & 3);
  const int q0 = qt * 64;

  const uint16_t* Q  = qb  + (size_t)bh * S_ * HD_;
  const uint16_t* Kp = kb  + (size_t)bh * S_ * HD_;
  const uint16_t* Vt = vtb + (size_t)bh * HD_ * S_;

  const int qrow = q0 + wave * 16;
  bf16x8 aq0 = *(const bf16x8*)(Q + (size_t)(qrow + l16) * HD_ + quad * 8);
  bf16x8 aq1 = *(const bf16x8*)(Q + (size_t)(qrow + l16) * HD_ + 32 + quad * 8);

  const int srow = lane >> 2;                       // local row 0..15
  const int schk = (lane & 3) ^ ((lane >> 3) & 3);  // swizzled source chunk
  const uint16_t* sb[4]; uint16_t* sd0[4]; uint16_t* sd1[4]; int sstep[4];
  #pragma unroll
  for (int j = 0; j < 4; ++j) {
    const int g = wave * 4 + j;
    if (g < 8) {
      const int c = (g >> 2) & 1, rb = g & 3;
      sd0[j] = &ks[0][c][rb * 512];
      sd1[j] = &ks[1][c][rb * 512];
      sb[j] = Kp + (size_t)(rb * 16 + srow) * HD_ + c * 32 + schk * 8;
      sstep[j] = 64 * HD_;          // advance 64 key-rows per tile
    } else {
      const int gg = g - 8, c = (gg >> 2) & 1, rb = gg & 3;
      sd0[j] = &vs[0][c][rb * 512];
      sd1[j] = &vs[1][c][rb * 512];
      sb[j] = Vt + (size_t)(rb * 16 + srow) * S_ + c * 32 + schk * 8;
      sstep[j] = 64;                // advance 64 key-cols per tile
    }
  }

  float lpart[4];
  f32x4 o[4];
  #pragma unroll
  for (int r = 0; r < 4; ++r) lpart[r] = 0.f;
  #pragma unroll
  for (int t = 0; t < 4; ++t)
    #pragma unroll
    for (int e = 0; e < 4; ++e) o[t][e] = 0.f;

  const int rowid = qrow + quad * 4;

  #pragma unroll
  for (int j = 0; j < 4; ++j) {
    g2l16(sb[j], sd0[j]);
    sb[j] += sstep[j];
  }
  __syncthreads();

  for (int kt = 0; kt <= qt; ++kt) {
    const int kbase = kt * 64;
    const bool diag = (kt == qt);
    const int cb = kt & 1;

    if (kt < qt) {
      #pragma unroll
      for (int j = 0; j < 4; ++j) {
        g2l16(sb[j], cb ? sd0[j] : sd1[j]);
        sb[j] += sstep[j];
      }
    }

    bf16x8 kf0[4], kf1[4];
    #pragma unroll
    for (int nt = 0; nt < 4; ++nt) {
      kf0[nt] = *(const bf16x8*)(&ks[cb][0][((nt * 16 + l16) * 4 + sw) * 8]);
      kf1[nt] = *(const bf16x8*)(&ks[cb][1][((nt * 16 + l16) * 4 + sw) * 8]);
    }
    f32x4 sacc[4];
    __builtin_amdgcn_s_setprio(1);
    #pragma unroll
    for (int nt = 0; nt < 4; ++nt) {
      #pragma unroll
      for (int e = 0; e < 4; ++e) sacc[nt][e] = 0.f;
      sacc[nt] = __builtin_amdgcn_mfma_f32_16x16x32_bf16(aq0, kf0[nt], sacc[nt], 0, 0, 0);
      sacc[nt] = __builtin_amdgcn_mfma_f32_16x16x32_bf16(aq1, kf1[nt], sacc[nt], 0, 0, 0);
    }
    __builtin_amdgcn_s_setprio(0);

    bf16x8 vf0[4], vf1[4];
    #pragma unroll
    for (int t = 0; t < 4; ++t) {
      vf0[t] = *(const bf16x8*)(&vs[cb][0][((t * 16 + l16) * 4 + sw) * 8]);
      vf1[t] = *(const bf16x8*)(&vs[cb][1][((t * 16 + l16) * 4 + sw) * 8]);
    }

    #pragma unroll
    for (int nt = 0; nt < 4; ++nt) {
      const int kkc = kbase + nt * 16 + l16;
      #pragma unroll
      for (int r = 0; r < 4; ++r) {
        float p = __builtin_amdgcn_exp2f(sacc[nt][r]);
        if (diag && (kkc > rowid + r)) p = 0.f;
        lpart[r] += p;
        p_lds[wave][quad * 4 + r][nt * 16 + l16] = f32_to_bf16_rtz(p);
      }
    }

    bf16x8 ap0 = *(const bf16x8*)(&p_lds[wave][l16][quad * 8]);
    bf16x8 ap1 = *(const bf16x8*)(&p_lds[wave][l16][32 + quad * 8]);
    __builtin_amdgcn_s_setprio(1);
    #pragma unroll
    for (int t = 0; t < 4; ++t) {
      o[t] = __builtin_amdgcn_mfma_f32_16x16x32_bf16(ap0, vf0[t], o[t], 0, 0, 0);
      o[t] = __builtin_amdgcn_mfma_f32_16x16x32_bf16(ap1, vf1[t], o[t], 0, 0, 0);
    }
    __builtin_amdgcn_s_setprio(0);
    __syncthreads();
  }

  #pragma unroll
  for (int r = 0; r < 4; ++r) {
    lpart[r] += __shfl_xor(lpart[r], 1, 64);
    lpart[r] += __shfl_xor(lpart[r], 2, 64);
    lpart[r] += __shfl_xor(lpart[r], 4, 64);
    lpart[r] += __shfl_xor(lpart[r], 8, 64);
  }
  const int bb = bh >> 4, h = bh & 15;    // kt index for packed out = h
  #pragma unroll
  for (int t = 0; t < 4; ++t) {
    const int c8 = t * 2 + (l16 >> 3);    // col-in-ktile / 8
    const int hh = c8 >> 2, c4 = c8 & 3, e = l16 & 7;
    #pragma unroll
    for (int r = 0; r < 4; ++r) {
      const float ov = o[t][r] / lpart[r];
      const int grow = bb * S_ + rowid + r;
      const int rt = grow >> 7, rr = grow & 127;
      const int s = 4 * rr + (c4 ^ ((rr >> 1) & 3));
      ao[POFF(rt, h, hh) + s * 8 + e] = f32_to_bf16(ov);
    }
  }
}

// out_gemm v4: 128x128 tile from PACKED aob/wfb, dbuf prefetch loop.
__global__ __launch_bounds__(256, 2)
void out_gemm(const uint16_t* __restrict__ ab, const uint16_t* __restrict__ wfb,
              const float* __restrict__ bfv, float* __restrict__ out)
{
  __shared__ __align__(16) uint16_t As[2][2][4096];
  __shared__ __align__(16) uint16_t Bs[2][2][4096];
  const int nsel = blockIdx.x;               // 8 weight N-tiles
  const int mtile = blockIdx.y;              // 32 m-tiles
  const int tid  = threadIdx.x;
  const int lane = tid & 63, wave = tid >> 6;
  const int quad = lane >> 4, l16 = lane & 15;
  const int wm = (wave >> 1) * 64, wn = (wave & 1) * 64;
  const int sw = quad ^ ((l16 >> 1) & 3);

  const int se0 = tid * 8, se1 = (256 + tid) * 8;
  const int ld0 = (wave * 64) * 8, ld1 = (256 + wave * 64) * 8;

  f32x4 acc[4][4];
  #pragma unroll
  for (int i = 0; i < 4; ++i)
    #pragma unroll
    for (int j = 0; j < 4; ++j)
      #pragma unroll
      for (int e = 0; e < 4; ++e)
        acc[i][j][e] = 0.f;

  #pragma unroll
  for (int h = 0; h < 2; ++h) {
    g2l16(ab  + POFF(mtile, 0, h) + se0, &As[0][h][ld0]);
    g2l16(ab  + POFF(mtile, 0, h) + se1, &As[0][h][ld1]);
    g2l16(wfb + POFF(nsel, 0, h) + se0, &Bs[0][h][ld0]);
    g2l16(wfb + POFF(nsel, 0, h) + se1, &Bs[0][h][ld1]);
  }
  __syncthreads();

  for (int t = 0; t < 16; ++t) {
    const int cb = t & 1, cn = cb ^ 1;
    if (t < 15) {
      #pragma unroll
      for (int h = 0; h < 2; ++h) {
        g2l16(ab  + POFF(mtile, t + 1, h) + se0, &As[cn][h][ld0]);
        g2l16(ab  + POFF(mtile, t + 1, h) + se1, &As[cn][h][ld1]);
        g2l16(wfb + POFF(nsel, t + 1, h) + se0, &Bs[cn][h][ld0]);
        g2l16(wfb + POFF(nsel, t + 1, h) + se1, &Bs[cn][h][ld1]);
      }
    }
    bf16x8 af[4][2], bf[4][2];
    #pragma unroll
    for (int mt = 0; mt < 4; ++mt) {
      const int ro = ((wm + mt * 16 + l16) * 4 + sw) * 8;
      af[mt][0] = *(const bf16x8*)(&As[cb][0][ro]);
      af[mt][1] = *(const bf16x8*)(&As[cb][1][ro]);
    }
    #pragma unroll
    for (int nt = 0; nt < 4; ++nt) {
      const int ro = ((wn + nt * 16 + l16) * 4 + sw) * 8;
      bf[nt][0] = *(const bf16x8*)(&Bs[cb][0][ro]);
      bf[nt][1] = *(const bf16x8*)(&Bs[cb][1][ro]);
    }
    __builtin_amdgcn_s_setprio(1);
    #pragma unroll
    for (int mt = 0; mt < 4; ++mt)
      #pragma unroll
      for (int nt = 0; nt < 4; ++nt) {
        acc[mt][nt] = __builtin_amdgcn_mfma_f32_16x16x32_bf16(
            af[mt][0], bf[nt][0], acc[mt][nt], 0, 0, 0);
        acc[mt][nt] = __builtin_amdgcn_mfma_f32_16x16x32_bf16(
            af[mt][1], bf[nt][1], acc[mt][nt], 0, 0, 0);
      }
    __builtin_amdgcn_s_setprio(0);
    __syncthreads();
  }

  const int m0 = mtile * 128, n0 = nsel * 128;
  #pragma unroll
  for (int nt = 0; nt < 4; ++nt) {
    const int n = n0 + wn + nt * 16 + l16;
    const float bia = bfv[n];
    #pragma unroll
    for (int mt = 0; mt < 4; ++mt) {
      #pragma unroll
      for (int r = 0; r < 4; ++r) {
        const int m = m0 + wm + mt * 16 + quad * 4 + r;
        out[(size_t)m * D_ + n] = acc[mt][nt][r] + bia;
      }
    }
  }
}

extern "C" void kernel_launch(void* const* d_in, const int* in_sizes, int n_in,
                              void* d_out, int out_size, void* d_ws, size_t ws_size,
                              hipStream_t stream) {
  (void)in_sizes; (void)n_in; (void)out_size; (void)ws_size;
  const float* x  = (const float*)d_in[0];
  const float* Wq = (const float*)d_in[1];
  const float* bq = (const float*)d_in[2];
  const float* Wk = (const float*)d_in[3];
  const float* bk = (const float*)d_in[4];
  const float* Wv = (const float*)d_in[5];
  const float* bv = (const float*)d_in[6];
  const float* Wf = (const float*)d_in[7];
  const float* bf = (const float*)d_in[8];
  float* out = (float*)d_out;

  uint16_t* ws = (uint16_t*)d_ws;
  uint16_t* xb   = ws;
  uint16_t* wqb  = xb  + (size_t)M_ * D_;
  uint16_t* wkb  = wqb + (size_t)D_ * D_;
  uint16_t* wvb  = wkb + (size_t)D_ * D_;
  uint16_t* wfb  = wvb + (size_t)D_ * D_;
  uint16_t* qbuf = wfb + (size_t)D_ * D_;
  uint16_t* kbuf = qbuf + (size_t)M_ * D_;
  uint16_t* vtb  = kbuf + (size_t)M_ * D_;
  uint16_t* aob  = vtb  + (size_t)M_ * D_;

  const int CAST_BLOCKS = (M_ * D_ / 8 + 4 * (D_ * D_ / 8)) / 256;   // 4096
  cast_pack<<<CAST_BLOCKS, 256, 0, stream>>>(x, Wq, Wk, Wv, Wf,
                                             xb, wqb, wkb, wvb, wfb);

  qkv_gemm<<<dim3(24, 16), 256, 0, stream>>>(xb, wqb, wkb, wvb, bq, bk, bv,
                                             qbuf, kbuf, vtb);
  flash_attn<<<dim3(32, 32), 256, 0, stream>>>(qbuf, kbuf, vtb, aob);
  out_gemm<<<dim3(8, 32), 256, 0, stream>>>(aob, wfb, bf, out);
}